// Round 6
// baseline (194.983 us; speedup 1.0000x reference)
//
#include <hip/hip_runtime.h>

#define PI_F 3.14159f

typedef _Float16 f16;
typedef __attribute__((ext_vector_type(8))) _Float16 f16x8;
typedef __attribute__((ext_vector_type(4))) _Float16 f16x4;
typedef __attribute__((ext_vector_type(4))) float f32x4;

#define AS1 __attribute__((address_space(1)))
#define AS3 __attribute__((address_space(3)))

__device__ __forceinline__ float fast_tanh(float x) {
    const float xc = fminf(fmaxf(x, -10.f), 10.f);
    const float t  = __expf(2.f * xc);
    return (t - 1.f) * __builtin_amdgcn_rcpf(t + 1.f);
}

// ---------------------------------------------------------------------------
// prep: Wt[1024][2048] fp16 head-organized (64 heads x 16 padded cols, pads 0)
// + bh[1024] f32. LDS-transposed: coalesced on both global sides.
// ---------------------------------------------------------------------------
__global__ void prep_kernel(const float* __restrict__ W_syn, const float* __restrict__ b_syn,
                            const float* __restrict__ W_sem, const float* __restrict__ b_sem,
                            const float* __restrict__ W_nar, const float* __restrict__ b_nar,
                            f16* __restrict__ Wt, float* __restrict__ bh)
{
    __shared__ float tile[16][65];
    const int blk = blockIdx.x;                  // 0..2047
    const int h = blk >> 5, k0 = (blk & 31) * 64;
    const float* W; const float* bb; int ld, base, width;
    if (h < 10)      { W = W_syn; bb = b_syn; ld = 100; base = h*10;      width = 10; }
    else if (h < 40) { W = W_sem; bb = b_sem; ld = 450; base = (h-10)*15; width = 15; }
    else             { W = W_nar; bb = b_nar; ld = 360; base = (h-40)*15; width = 15; }
    const int tid = threadIdx.x;
    {
        const int c = tid & 15, kr = tid >> 4;
        if (c < width)
#pragma unroll
            for (int ii = 0; ii < 4; ++ii)
                tile[c][kr + ii*16] = W[(size_t)(k0 + kr + ii*16) * ld + base + c];
    }
    __syncthreads();
    {
        const int c = tid >> 4, kq = (tid & 15) * 4;
        f16x4 v;
#pragma unroll
        for (int q = 0; q < 4; ++q)
            v[q] = (c < width) ? (f16)tile[c][kq + q] : (f16)0.0f;
        *(f16x4*)(Wt + (size_t)(h*16 + c) * 2048 + k0 + kq) = v;
    }
    if ((blk & 31) == 0 && tid < 16)
        bh[h*16 + tid] = (tid < width) ? bb[base + tid] : 0.0f;
}

// ---------------------------------------------------------------------------
// gemm_fused: 128x128 tile, BK=32, 4 waves, 2-phase double-buffered pipeline:
// STAGE(next) -> COMPUTE(cur) -> syncthreads (single vmcnt(0)+barrier per kt).
// Loads are in flight across the full compute phase (catalog T3-minimum).
// LDS 48KB (A fp32 16KB x2, B f16 8KB x2) -> 3 blocks/CU.
// Both-sides XOR swizzle: A slot j holds global j^(r&7); B: j^((r>>1)&3).
// ---------------------------------------------------------------------------
__global__ __launch_bounds__(256)
void gemm_fused_kernel(const float* __restrict__ X, const f16* __restrict__ Wt,
                       const float* __restrict__ bh, float* __restrict__ Out)
{
    __shared__ __align__(16) char smem[49152];
    constexpr int A0 = 0, A1 = 16384, B0 = 32768, B1 = 40960;
    f16 (*Cs)[136] = (f16(*)[136])smem;           // epilogue reuse (34.8 KB)

    const int tid  = threadIdx.x;
    // XCD-chunked bijective swizzle (nwg=1024 % 8 == 0)
    const int sw   = (blockIdx.x & 7) * 128 + (blockIdx.x >> 3);
    const int bm   = sw >> 3, bn = sw & 7;
    const int m0   = bm * 128, n0 = bn * 128;
    const int wave = tid >> 6, lane = tid & 63;
    const int wr   = (wave >> 1) * 64, wc = (wave & 1) * 64;
    const int l15  = lane & 15, l4 = lane >> 4;

    // per-thread swizzled global source pointers (advance by kt*32 elems)
    const float* srcA[4];
    const f16*   srcB[2];
#pragma unroll
    for (int i = 0; i < 4; ++i) {
        const int ac = (wave*4 + i)*64 + lane;    // LDS 16B-chunk 0..1023
        const int ar = ac >> 3, aj = ac & 7;
        srcA[i] = X + (size_t)(m0 + ar) * 2048 + ((aj ^ (ar & 7)) << 2);
    }
#pragma unroll
    for (int i = 0; i < 2; ++i) {
        const int bc = (wave*2 + i)*64 + lane;    // LDS 16B-chunk 0..511
        const int br = bc >> 2, bj = bc & 3;
        srcB[i] = Wt + (size_t)(n0 + br) * 2048 + ((bj ^ ((br >> 1) & 3)) << 3);
    }

    f32x4 acc[4][4] = {};

#define STAGE(ABASE, BBASE, KT) do {                                            \
    _Pragma("unroll")                                                           \
    for (int i_ = 0; i_ < 4; ++i_)                                              \
        __builtin_amdgcn_global_load_lds(                                       \
            (const AS1 void*)(srcA[i_] + (KT)*32),                              \
            (AS3 void*)(smem + (ABASE) + (wave*4 + i_)*1024), 16, 0, 0);        \
    _Pragma("unroll")                                                           \
    for (int i_ = 0; i_ < 2; ++i_)                                              \
        __builtin_amdgcn_global_load_lds(                                       \
            (const AS1 void*)(srcB[i_] + (KT)*32),                              \
            (AS3 void*)(smem + (BBASE) + (wave*2 + i_)*1024), 16, 0, 0);        \
} while (0)

#define COMPUTE(ABASE, BBASE) do {                                              \
    f16x8 af_[4], bf_[4];                                                       \
    _Pragma("unroll")                                                           \
    for (int mf_ = 0; mf_ < 4; ++mf_) {                                         \
        const int r_ = wr + mf_*16 + l15;                                       \
        const int s_ = r_ & 7;                                                  \
        const float4 lo_ = *(const float4*)(smem + (ABASE) + (r_*8 + ((l4*2)     ^ s_))*16); \
        const float4 hi_ = *(const float4*)(smem + (ABASE) + (r_*8 + ((l4*2 + 1) ^ s_))*16); \
        f16x8 a_;                                                               \
        a_[0]=(f16)lo_.x; a_[1]=(f16)lo_.y; a_[2]=(f16)lo_.z; a_[3]=(f16)lo_.w; \
        a_[4]=(f16)hi_.x; a_[5]=(f16)hi_.y; a_[6]=(f16)hi_.z; a_[7]=(f16)hi_.w; \
        af_[mf_] = a_;                                                          \
    }                                                                           \
    _Pragma("unroll")                                                           \
    for (int nf_ = 0; nf_ < 4; ++nf_) {                                         \
        const int r_ = wc + nf_*16 + l15;                                       \
        bf_[nf_] = *(const f16x8*)(smem + (BBASE) + (r_*4 + (l4 ^ ((r_>>1)&3)))*16); \
    }                                                                           \
    _Pragma("unroll")                                                           \
    for (int mf_ = 0; mf_ < 4; ++mf_)                                           \
        _Pragma("unroll")                                                       \
        for (int nf_ = 0; nf_ < 4; ++nf_)                                       \
            acc[mf_][nf_] = __builtin_amdgcn_mfma_f32_16x16x32_f16(             \
                af_[mf_], bf_[nf_], acc[mf_][nf_], 0, 0, 0);                    \
} while (0)

    STAGE(A0, B0, 0);
    __syncthreads();
    for (int it = 0; it < 32; ++it) {            // 2 kts per iteration, 64 total
        STAGE(A1, B1, 2*it + 1);
        COMPUTE(A0, B0);
        __syncthreads();
        if (it < 31) STAGE(A0, B0, 2*it + 2);
        COMPUTE(A1, B1);
        __syncthreads();
    }
#undef STAGE
#undef COMPUTE

    // ---- acc -> LDS (C/D: col=lane&15, row=(lane>>4)*4+reg) ----
#pragma unroll
    for (int mf = 0; mf < 4; ++mf)
#pragma unroll
        for (int nf = 0; nf < 4; ++nf)
#pragma unroll
            for (int r = 0; r < 4; ++r)
                Cs[wr + mf*16 + l4*4 + r][wc + nf*16 + l15] = (f16)acc[mf][nf][r];
    __syncthreads();

    // ---- fused epilogue: 4 (token,head) pairs per thread ----
#pragma unroll
    for (int p = 0; p < 4; ++p) {
        const int linear = p * 256 + tid;
        const int t  = linear >> 3;
        const int hh = linear & 7;
        const int H  = bn * 8 + hh;
        f16x8 y0 = *(const f16x8*)&Cs[t][hh * 16];
        f16x8 y1 = *(const f16x8*)&Cs[t][hh * 16 + 8];
        const float* bb = bh + H * 16;

        float Bv[16];
#pragma unroll
        for (int j = 0; j < 8; ++j) {
            Bv[j]     = fast_tanh((float)y0[j] + bb[j])     * PI_F;
            Bv[j + 8] = fast_tanh((float)y1[j] + bb[j + 8]) * PI_F;
        }
        float s2 = 0.f;
#pragma unroll
        for (int j = 0; j < 16; ++j) s2 += Bv[j] * Bv[j];
        const float theta = 0.5f * sqrtf(s2);
        const float sinc  = (theta > 1e-8f) ? (__sinf(theta) / theta) : 1.0f;
        const float cs    = __cosf(theta);
        const float scale = -0.5f * sinc;
        float C[16];
#pragma unroll
        for (int j = 0; j < 16; ++j) C[j] = Bv[j] * scale;

        float4 v0 = {0,0,0,0}, v1 = {0,0,0,0}, v2 = {0,0,0,0}, v3 = {0,0,0,0};
        float4 v4 = {0,0,0,0}, v5 = {0,0,0,0}, v6 = {0,0,0,0}, v7 = {0,0,0,0};
        v0.x = cs;
        if (H < 10) {                              // syn: biv 6..15
            v1.z=C[0]; v1.w=C[1];
            v2.x=C[2]; v2.y=C[3]; v2.z=C[4]; v2.w=C[5];
            v3.x=C[6]; v3.y=C[7]; v3.z=C[8]; v3.w=C[9];
        } else if (H < 40) {                       // sem: vec 1..5 + biv 6..15
            v0.y=C[0]; v0.z=C[1]; v0.w=C[2];
            v1.x=C[3]; v1.y=C[4]; v1.z=C[5]; v1.w=C[6];
            v2.x=C[7]; v2.y=C[8]; v2.z=C[9]; v2.w=C[10];
            v3.x=C[11]; v3.y=C[12]; v3.z=C[13]; v3.w=C[14];
        } else {                                   // nar: biv 6..15 + quad 26..30
            v1.z=C[0]; v1.w=C[1];
            v2.x=C[2]; v2.y=C[3]; v2.z=C[4]; v2.w=C[5];
            v3.x=C[6]; v3.y=C[7]; v3.z=C[8]; v3.w=C[9];
            v6.z=C[10]; v6.w=C[11];
            v7.x=C[12]; v7.y=C[13]; v7.z=C[14];
        }
        float4* dst = (float4*)(Out + ((size_t)(m0 + t) * 64 + H) * 32);
        dst[0]=v0; dst[1]=v1; dst[2]=v2; dst[3]=v3;
        dst[4]=v4; dst[5]=v5; dst[6]=v6; dst[7]=v7;
    }
}

// ---------------------------------------------------------------------------
extern "C" void kernel_launch(void* const* d_in, const int* in_sizes, int n_in,
                              void* d_out, int out_size, void* d_ws, size_t ws_size,
                              hipStream_t stream)
{
    const float* x     = (const float*)d_in[0];
    const float* W_syn = (const float*)d_in[1];
    const float* b_syn = (const float*)d_in[2];
    const float* W_sem = (const float*)d_in[3];
    const float* b_sem = (const float*)d_in[4];
    const float* W_nar = (const float*)d_in[5];
    const float* b_nar = (const float*)d_in[6];

    // ws: Wt fp16 4MB | bh f32 4KB  => 4.2MB
    f16*   Wt = (f16*)d_ws;
    float* bh = (float*)((char*)d_ws + (size_t)4*1024*1024);
    float* Out = (float*)d_out;

    prep_kernel<<<2048, 256, 0, stream>>>(W_syn, b_syn, W_sem, b_sem, W_nar, b_nar, Wt, bh);
    gemm_fused_kernel<<<1024, 256, 0, stream>>>(x, Wt, bh, Out);
}

// Round 7
// 169.438 us; speedup vs baseline: 1.1508x; 1.1508x over previous
//
#include <hip/hip_runtime.h>

#define PI_F 3.14159f

typedef _Float16 f16;
typedef __attribute__((ext_vector_type(8))) _Float16 f16x8;
typedef __attribute__((ext_vector_type(4))) _Float16 f16x4;
typedef __attribute__((ext_vector_type(4))) float f32x4;

#define AS1 __attribute__((address_space(1)))
#define AS3 __attribute__((address_space(3)))

__device__ __forceinline__ float fast_tanh(float x) {
    const float xc = fminf(fmaxf(x, -10.f), 10.f);
    const float t  = __expf(2.f * xc);
    return (t - 1.f) * __builtin_amdgcn_rcpf(t + 1.f);
}

// ---------------------------------------------------------------------------
// convert: X fp32 -> Xh fp16 (8 elems/thread, float4 x2 in, f16x8 out)
// ---------------------------------------------------------------------------
__global__ __launch_bounds__(256)
void convert_kernel(const float* __restrict__ X, f16* __restrict__ Xh)
{
    const size_t i = ((size_t)blockIdx.x * 256 + threadIdx.x) * 8;
    const float4 a = *(const float4*)(X + i);
    const float4 b = *(const float4*)(X + i + 4);
    f16x8 v;
    v[0]=(f16)a.x; v[1]=(f16)a.y; v[2]=(f16)a.z; v[3]=(f16)a.w;
    v[4]=(f16)b.x; v[5]=(f16)b.y; v[6]=(f16)b.z; v[7]=(f16)b.w;
    *(f16x8*)(Xh + i) = v;
}

// ---------------------------------------------------------------------------
// prep: Wt[1024][2048] fp16 head-organized (64 heads x 16 padded cols, pads 0)
// + bh[1024] f32. LDS-transposed: coalesced on both global sides.
// ---------------------------------------------------------------------------
__global__ void prep_kernel(const float* __restrict__ W_syn, const float* __restrict__ b_syn,
                            const float* __restrict__ W_sem, const float* __restrict__ b_sem,
                            const float* __restrict__ W_nar, const float* __restrict__ b_nar,
                            f16* __restrict__ Wt, float* __restrict__ bh)
{
    __shared__ float tile[16][65];
    const int blk = blockIdx.x;                  // 0..2047
    const int h = blk >> 5, k0 = (blk & 31) * 64;
    const float* W; const float* bb; int ld, base, width;
    if (h < 10)      { W = W_syn; bb = b_syn; ld = 100; base = h*10;      width = 10; }
    else if (h < 40) { W = W_sem; bb = b_sem; ld = 450; base = (h-10)*15; width = 15; }
    else             { W = W_nar; bb = b_nar; ld = 360; base = (h-40)*15; width = 15; }
    const int tid = threadIdx.x;
    {
        const int c = tid & 15, kr = tid >> 4;
        if (c < width)
#pragma unroll
            for (int ii = 0; ii < 4; ++ii)
                tile[c][kr + ii*16] = W[(size_t)(k0 + kr + ii*16) * ld + base + c];
    }
    __syncthreads();
    {
        const int c = tid >> 4, kq = (tid & 15) * 4;
        f16x4 v;
#pragma unroll
        for (int q = 0; q < 4; ++q)
            v[q] = (c < width) ? (f16)tile[c][kq + q] : (f16)0.0f;
        *(f16x4*)(Wt + (size_t)(h*16 + c) * 2048 + k0 + kq) = v;
    }
    if ((blk & 31) == 0 && tid < 16)
        bh[h*16 + tid] = (tid < width) ? bb[base + tid] : 0.0f;
}

// ---------------------------------------------------------------------------
// Shared epilogue: Cs is a 128x128 f16 LDS tile, granule-swizzled with
// G = (col>>3) ^ (row & 15). Reads are 2 x ds_read_b128 per (token,head).
// ---------------------------------------------------------------------------
__device__ __forceinline__ void rotor_epilogue(const f16* Cs, int tid, int m0, int bn,
                                               const float* __restrict__ bh,
                                               float* __restrict__ Out)
{
#pragma unroll
    for (int p = 0; p < 4; ++p) {
        const int linear = p * 256 + tid;
        const int t  = linear >> 3;                // token-in-tile 0..127
        const int hh = linear & 7;                 // head-in-tile 0..7
        const int H  = bn * 8 + hh;
        const int g0 = (2*hh)     ^ (t & 15);
        const int g1 = (2*hh + 1) ^ (t & 15);
        f16x8 y0 = *(const f16x8*)(Cs + t*128 + g0*8);
        f16x8 y1 = *(const f16x8*)(Cs + t*128 + g1*8);
        const float* bb = bh + H * 16;

        float Bv[16];
#pragma unroll
        for (int j = 0; j < 8; ++j) {
            Bv[j]     = fast_tanh((float)y0[j] + bb[j])     * PI_F;
            Bv[j + 8] = fast_tanh((float)y1[j] + bb[j + 8]) * PI_F;
        }
        float s2 = 0.f;
#pragma unroll
        for (int j = 0; j < 16; ++j) s2 += Bv[j] * Bv[j];
        const float theta = 0.5f * sqrtf(s2);
        const float sinc  = (theta > 1e-8f) ? (__sinf(theta) / theta) : 1.0f;
        const float cs    = __cosf(theta);
        const float scale = -0.5f * sinc;
        float C[16];
#pragma unroll
        for (int j = 0; j < 16; ++j) C[j] = Bv[j] * scale;

        float4 v0 = {0,0,0,0}, v1 = {0,0,0,0}, v2 = {0,0,0,0}, v3 = {0,0,0,0};
        float4 v4 = {0,0,0,0}, v5 = {0,0,0,0}, v6 = {0,0,0,0}, v7 = {0,0,0,0};
        v0.x = cs;
        if (H < 10) {                              // syn: biv 6..15
            v1.z=C[0]; v1.w=C[1];
            v2.x=C[2]; v2.y=C[3]; v2.z=C[4]; v2.w=C[5];
            v3.x=C[6]; v3.y=C[7]; v3.z=C[8]; v3.w=C[9];
        } else if (H < 40) {                       // sem: vec 1..5 + biv 6..15
            v0.y=C[0]; v0.z=C[1]; v0.w=C[2];
            v1.x=C[3]; v1.y=C[4]; v1.z=C[5]; v1.w=C[6];
            v2.x=C[7]; v2.y=C[8]; v2.z=C[9]; v2.w=C[10];
            v3.x=C[11]; v3.y=C[12]; v3.z=C[13]; v3.w=C[14];
        } else {                                   // nar: biv 6..15 + quad 26..30
            v1.z=C[0]; v1.w=C[1];
            v2.x=C[2]; v2.y=C[3]; v2.z=C[4]; v2.w=C[5];
            v3.x=C[6]; v3.y=C[7]; v3.z=C[8]; v3.w=C[9];
            v6.z=C[10]; v6.w=C[11];
            v7.x=C[12]; v7.y=C[13]; v7.z=C[14];
        }
        float4* dst = (float4*)(Out + ((size_t)(m0 + t) * 64 + H) * 32);
        dst[0]=v0; dst[1]=v1; dst[2]=v2; dst[3]=v3;
        dst[4]=v4; dst[5]=v5; dst[6]=v6; dst[7]=v7;
    }
}

// ---------------------------------------------------------------------------
// FAST PATH gemm: all-fp16 operands, 128x128 tile, BK=64, single-buffered
// 32KB LDS -> 5 blocks/CU (m103-verified structure). Both-sides granule
// swizzle g^(r&7) -> conflict-minimal ds_read_b128. Fused rotor epilogue.
// ---------------------------------------------------------------------------
__global__ __launch_bounds__(256)
void gemm_fp16_kernel(const f16* __restrict__ Xh, const f16* __restrict__ Wt,
                      const float* __restrict__ bh, float* __restrict__ Out)
{
    __shared__ __align__(16) char smem[32768];   // A 16KB | B 16KB; reused as Cs
    const int tid  = threadIdx.x;
    const int sw   = (blockIdx.x & 7) * 128 + (blockIdx.x >> 3);  // XCD-chunked
    const int bm   = sw >> 3, bn = sw & 7;
    const int m0   = bm * 128, n0 = bn * 128;
    const int wave = tid >> 6, lane = tid & 63;
    const int wr   = (wave >> 1) * 64, wc = (wave & 1) * 64;
    const int l15  = lane & 15, l4 = lane >> 4;

    // staging sources (granule-swizzled): chunk c -> row r=c>>3, slot j=c&7
    const f16* srcA[4]; const f16* srcB[4];
#pragma unroll
    for (int i = 0; i < 4; ++i) {
        const int c = (wave*4 + i)*64 + lane;     // 0..1023
        const int r = c >> 3, j = c & 7;
        srcA[i] = Xh + (size_t)(m0 + r) * 2048 + ((j ^ (r & 7)) << 3);
        srcB[i] = Wt + (size_t)(n0 + r) * 2048 + ((j ^ (r & 7)) << 3);
    }

    f32x4 acc[4][4] = {};

    for (int kt = 0; kt < 32; ++kt) {
        const int kof = kt * 64;
#pragma unroll
        for (int i = 0; i < 4; ++i)
            __builtin_amdgcn_global_load_lds((const AS1 void*)(srcA[i] + kof),
                (AS3 void*)(smem + (wave*4 + i) * 1024), 16, 0, 0);
#pragma unroll
        for (int i = 0; i < 4; ++i)
            __builtin_amdgcn_global_load_lds((const AS1 void*)(srcB[i] + kof),
                (AS3 void*)(smem + 16384 + (wave*4 + i) * 1024), 16, 0, 0);
        __syncthreads();                          // drains vmcnt before barrier
#pragma unroll
        for (int ks = 0; ks < 2; ++ks) {
            f16x8 af[4], bf[4];
#pragma unroll
            for (int mf = 0; mf < 4; ++mf) {
                const int r = wr + mf*16 + l15;
                const int g = (ks*4 + l4) ^ (r & 7);
                af[mf] = *(const f16x8*)(smem + r*128 + g*16);
            }
#pragma unroll
            for (int nf = 0; nf < 4; ++nf) {
                const int r = wc + nf*16 + l15;
                const int g = (ks*4 + l4) ^ (r & 7);
                bf[nf] = *(const f16x8*)(smem + 16384 + r*128 + g*16);
            }
#pragma unroll
            for (int mf = 0; mf < 4; ++mf)
#pragma unroll
                for (int nf = 0; nf < 4; ++nf)
                    acc[mf][nf] = __builtin_amdgcn_mfma_f32_16x16x32_f16(af[mf], bf[nf], acc[mf][nf], 0, 0, 0);
        }
        __syncthreads();                          // LDS free before next DMA
    }

    // ---- acc -> Cs (granule-swizzled [128][128] f16 over full 32KB) ----
    f16* Cs = (f16*)smem;
#pragma unroll
    for (int mf = 0; mf < 4; ++mf)
#pragma unroll
        for (int nf = 0; nf < 4; ++nf)
#pragma unroll
            for (int r = 0; r < 4; ++r) {
                const int R = wr + mf*16 + l4*4 + r;
                const int col = wc + nf*16 + l15;
                const int G = (col >> 3) ^ (R & 15);
                Cs[R*128 + G*8 + (col & 7)] = (f16)acc[mf][nf][r];
            }
    __syncthreads();
    rotor_epilogue(Cs, tid, m0, bn, bh, Out);
}

// ---------------------------------------------------------------------------
// FALLBACK gemm (R5 structure, proven 173.9us): fp32 A staged via
// global_load_lds, cvt at fragment read; 48KB LDS.
// ---------------------------------------------------------------------------
__global__ __launch_bounds__(256)
void gemm_f32a_kernel(const float* __restrict__ X, const f16* __restrict__ Wt,
                      const float* __restrict__ bh, float* __restrict__ Out)
{
    __shared__ __align__(16) char smem[49152];
    float* Asf = (float*)smem;
    f16*   Bsh = (f16*)(smem + 32768);

    const int tid  = threadIdx.x;
    const int sw   = (blockIdx.x & 7) * 128 + (blockIdx.x >> 3);
    const int bm   = sw >> 3, bn = sw & 7;
    const int m0   = bm * 128, n0 = bn * 128;
    const int wave = tid >> 6, lane = tid & 63;
    const int wr   = (wave >> 1) * 64, wc = (wave & 1) * 64;
    const int l15  = lane & 15, l4 = lane >> 4;

    f32x4 acc[4][4] = {};

    for (int kt = 0; kt < 32; ++kt) {
        const int kof = kt * 64;
#pragma unroll
        for (int i = 0; i < 8; ++i) {
            const int ac = (wave*8 + i)*64 + lane;
            const int ar = ac >> 4;
            const int agc = (ac & 15) ^ (ar & 15);
            const float* src = X + (size_t)(m0 + ar) * 2048 + kof + agc * 4;
            __builtin_amdgcn_global_load_lds((const AS1 void*)src,
                (AS3 void*)(smem + (wave*8 + i) * 1024), 16, 0, 0);
        }
#pragma unroll
        for (int i = 0; i < 4; ++i) {
            const int bc = (wave*4 + i)*64 + lane;
            const int br = bc >> 3;
            const int bgc = (bc & 7) ^ (br & 7);
            const f16* src = Wt + (size_t)(n0 + br) * 2048 + kof + bgc * 8;
            __builtin_amdgcn_global_load_lds((const AS1 void*)src,
                (AS3 void*)(smem + 32768 + (wave*4 + i) * 1024), 16, 0, 0);
        }
        __syncthreads();
#pragma unroll
        for (int ks = 0; ks < 2; ++ks) {
            f16x8 af[4], bf[4];
#pragma unroll
            for (int mf = 0; mf < 4; ++mf) {
                const int r  = wr + mf*16 + l15;
                const int s  = r & 15;
                const float4 lo = *(const float4*)(Asf + ((size_t)r*16 + ((ks*8 + l4*2)     ^ s)) * 4);
                const float4 hi = *(const float4*)(Asf + ((size_t)r*16 + ((ks*8 + l4*2 + 1) ^ s)) * 4);
                f16x8 a;
                a[0]=(f16)lo.x; a[1]=(f16)lo.y; a[2]=(f16)lo.z; a[3]=(f16)lo.w;
                a[4]=(f16)hi.x; a[5]=(f16)hi.y; a[6]=(f16)hi.z; a[7]=(f16)hi.w;
                af[mf] = a;
            }
#pragma unroll
            for (int nf = 0; nf < 4; ++nf) {
                const int r = wc + nf*16 + l15;
                bf[nf] = *(const f16x8*)(Bsh + ((size_t)r*8 + ((ks*4 + l4) ^ (r & 7))) * 8);
            }
#pragma unroll
            for (int mf = 0; mf < 4; ++mf)
#pragma unroll
                for (int nf = 0; nf < 4; ++nf)
                    acc[mf][nf] = __builtin_amdgcn_mfma_f32_16x16x32_f16(af[mf], bf[nf], acc[mf][nf], 0, 0, 0);
        }
        __syncthreads();
    }

    f16* Cs = (f16*)smem;     // reuse as [128][128] granule-swizzled
#pragma unroll
    for (int mf = 0; mf < 4; ++mf)
#pragma unroll
        for (int nf = 0; nf < 4; ++nf)
#pragma unroll
            for (int r = 0; r < 4; ++r) {
                const int R = wr + mf*16 + l4*4 + r;
                const int col = wc + nf*16 + l15;
                const int G = (col >> 3) ^ (R & 15);
                Cs[R*128 + G*8 + (col & 7)] = (f16)acc[mf][nf][r];
            }
    __syncthreads();
    rotor_epilogue(Cs, tid, m0, bn, bh, Out);
}

// ---------------------------------------------------------------------------
extern "C" void kernel_launch(void* const* d_in, const int* in_sizes, int n_in,
                              void* d_out, int out_size, void* d_ws, size_t ws_size,
                              hipStream_t stream)
{
    const float* x     = (const float*)d_in[0];
    const float* W_syn = (const float*)d_in[1];
    const float* b_syn = (const float*)d_in[2];
    const float* W_sem = (const float*)d_in[3];
    const float* b_sem = (const float*)d_in[4];
    const float* W_nar = (const float*)d_in[5];
    const float* b_nar = (const float*)d_in[6];

    // ws layout: Wt fp16 4MB | bh f32 (64KB slot) | Xh fp16 64MB
    const size_t WT_B = (size_t)4*1024*1024, BH_B = 65536;
    const size_t XH_B = (size_t)33554432 * 2;
    f16*   Wt = (f16*)d_ws;
    float* bh = (float*)((char*)d_ws + WT_B);
    f16*   Xh = (f16*)((char*)d_ws + WT_B + BH_B);
    float* Out = (float*)d_out;

    prep_kernel<<<2048, 256, 0, stream>>>(W_syn, b_syn, W_sem, b_sem, W_nar, b_nar, Wt, bh);
    if (ws_size >= WT_B + BH_B + XH_B) {
        convert_kernel<<<16384, 256, 0, stream>>>(x, Xh);
        gemm_fp16_kernel<<<1024, 256, 0, stream>>>(Xh, Wt, bh, Out);
    } else {
        gemm_f32a_kernel<<<1024, 256, 0, stream>>>(x, Wt, bh, Out);
    }
}

// Round 8
// 147.989 us; speedup vs baseline: 1.3176x; 1.1449x over previous
//
#include <hip/hip_runtime.h>

#define PI_F 3.14159f

typedef _Float16 f16;
typedef __attribute__((ext_vector_type(8))) _Float16 f16x8;
typedef __attribute__((ext_vector_type(4))) _Float16 f16x4;
typedef __attribute__((ext_vector_type(4))) float f32x4;

#define AS1 __attribute__((address_space(1)))
#define AS3 __attribute__((address_space(3)))

__device__ __forceinline__ float fast_tanh(float x) {
    const float xc = fminf(fmaxf(x, -10.f), 10.f);
    const float t  = __expf(2.f * xc);
    return (t - 1.f) * __builtin_amdgcn_rcpf(t + 1.f);
}

// ---------------------------------------------------------------------------
// convert: X fp32 -> Xh fp16
// ---------------------------------------------------------------------------
__global__ __launch_bounds__(256)
void convert_kernel(const float* __restrict__ X, f16* __restrict__ Xh)
{
    const size_t i = ((size_t)blockIdx.x * 256 + threadIdx.x) * 8;
    const float4 a = *(const float4*)(X + i);
    const float4 b = *(const float4*)(X + i + 4);
    f16x8 v;
    v[0]=(f16)a.x; v[1]=(f16)a.y; v[2]=(f16)a.z; v[3]=(f16)a.w;
    v[4]=(f16)b.x; v[5]=(f16)b.y; v[6]=(f16)b.z; v[7]=(f16)b.w;
    *(f16x8*)(Xh + i) = v;
}

// ---------------------------------------------------------------------------
// prep: Wt[1024][2048] fp16 head-organized (64 heads x 16 padded cols, pads 0)
// + bh[1024] f32. LDS-transposed: coalesced on both global sides.
// ---------------------------------------------------------------------------
__global__ void prep_kernel(const float* __restrict__ W_syn, const float* __restrict__ b_syn,
                            const float* __restrict__ W_sem, const float* __restrict__ b_sem,
                            const float* __restrict__ W_nar, const float* __restrict__ b_nar,
                            f16* __restrict__ Wt, float* __restrict__ bh)
{
    __shared__ float tile[16][65];
    const int blk = blockIdx.x;                  // 0..2047
    const int h = blk >> 5, k0 = (blk & 31) * 64;
    const float* W; const float* bb; int ld, base, width;
    if (h < 10)      { W = W_syn; bb = b_syn; ld = 100; base = h*10;      width = 10; }
    else if (h < 40) { W = W_sem; bb = b_sem; ld = 450; base = (h-10)*15; width = 15; }
    else             { W = W_nar; bb = b_nar; ld = 360; base = (h-40)*15; width = 15; }
    const int tid = threadIdx.x;
    {
        const int c = tid & 15, kr = tid >> 4;
        if (c < width)
#pragma unroll
            for (int ii = 0; ii < 4; ++ii)
                tile[c][kr + ii*16] = W[(size_t)(k0 + kr + ii*16) * ld + base + c];
    }
    __syncthreads();
    {
        const int c = tid >> 4, kq = (tid & 15) * 4;
        f16x4 v;
#pragma unroll
        for (int q = 0; q < 4; ++q)
            v[q] = (c < width) ? (f16)tile[c][kq + q] : (f16)0.0f;
        *(f16x4*)(Wt + (size_t)(h*16 + c) * 2048 + k0 + kq) = v;
    }
    if ((blk & 31) == 0 && tid < 16)
        bh[h*16 + tid] = (tid < width) ? bb[base + tid] : 0.0f;
}

// ---------------------------------------------------------------------------
// FAST PATH gemm: 256x256 tile, BK=64, 8 waves (2Mx4N), 2-phase double-buffered
// K-loop (STAGE next -> COMPUTE cur -> single __syncthreads per K-tile).
// LDS 128KB (A 32KB + B 32KB, x2 buffers) -> 1 block/CU. Granule swizzle
// j^(r&7) both sides (R7-validated, 0 bank conflicts). Fused rotor epilogue.
// ---------------------------------------------------------------------------
__global__ __launch_bounds__(512, 2)
void gemm256_kernel(const f16* __restrict__ Xh, const f16* __restrict__ Wt,
                    const float* __restrict__ bh, float* __restrict__ Out)
{
    __shared__ __align__(16) char smem[131072];   // [buf:65536][A:32768|B:32768]
    const int tid  = threadIdx.x;
    // XCD-chunked bijective swizzle (nwg=256 % 8 == 0)
    const int sw   = (blockIdx.x & 7) * 32 + (blockIdx.x >> 3);
    const int bm   = sw >> 2, bn = sw & 3;
    const int m0   = bm * 256, n0 = bn * 256;
    const int wave = tid >> 6, lane = tid & 63;
    const int wm   = wave >> 2, wn = wave & 3;
    const int wrow = wm * 128, wcol = wn * 64;    // per-wave 128x64 output
    const int l15  = lane & 15, l4 = lane >> 4;

    // staging sources, granule-swizzled: LDS chunk c holds global slot (c&7)^(r&7)
    const f16* srcA[4]; const f16* srcB[4];
#pragma unroll
    for (int i = 0; i < 4; ++i) {
        const int c = i * 512 + tid;              // 0..2047
        const int r = c >> 3, j = c & 7;
        srcA[i] = Xh + (size_t)(m0 + r) * 2048 + ((j ^ (r & 7)) << 3);
        srcB[i] = Wt + (size_t)(n0 + r) * 2048 + ((j ^ (r & 7)) << 3);
    }

    f32x4 acc[8][4] = {};

#define STAGE(DBUF, KT) do {                                                    \
    const int ko_ = (KT) * 64;                                                  \
    const int ab_ = (DBUF) * 65536;                                             \
    _Pragma("unroll")                                                           \
    for (int i_ = 0; i_ < 4; ++i_)                                              \
        __builtin_amdgcn_global_load_lds((const AS1 void*)(srcA[i_] + ko_),     \
            (AS3 void*)(smem + ab_ + i_*8192 + tid*16), 16, 0, 0);              \
    _Pragma("unroll")                                                           \
    for (int i_ = 0; i_ < 4; ++i_)                                              \
        __builtin_amdgcn_global_load_lds((const AS1 void*)(srcB[i_] + ko_),     \
            (AS3 void*)(smem + ab_ + 32768 + i_*8192 + tid*16), 16, 0, 0);      \
} while (0)

#define COMPUTE(DBUF) do {                                                      \
    const int bs_ = (DBUF) * 65536;                                             \
    _Pragma("unroll")                                                           \
    for (int ks_ = 0; ks_ < 2; ++ks_) {                                         \
        f16x8 af_[8], bf_[4];                                                   \
        _Pragma("unroll")                                                       \
        for (int mf_ = 0; mf_ < 8; ++mf_) {                                     \
            const int r_ = wrow + mf_*16 + l15;                                 \
            const int g_ = (ks_*4 + l4) ^ (r_ & 7);                             \
            af_[mf_] = *(const f16x8*)(smem + bs_ + r_*128 + g_*16);            \
        }                                                                       \
        _Pragma("unroll")                                                       \
        for (int nf_ = 0; nf_ < 4; ++nf_) {                                     \
            const int r_ = wcol + nf_*16 + l15;                                 \
            const int g_ = (ks_*4 + l4) ^ (r_ & 7);                             \
            bf_[nf_] = *(const f16x8*)(smem + bs_ + 32768 + r_*128 + g_*16);    \
        }                                                                       \
        _Pragma("unroll")                                                       \
        for (int mf_ = 0; mf_ < 8; ++mf_)                                       \
            _Pragma("unroll")                                                   \
            for (int nf_ = 0; nf_ < 4; ++nf_)                                   \
                acc[mf_][nf_] = __builtin_amdgcn_mfma_f32_16x16x32_f16(         \
                    af_[mf_], bf_[nf_], acc[mf_][nf_], 0, 0, 0);                \
    }                                                                           \
} while (0)

    STAGE(0, 0);
    __syncthreads();                              // drain prologue loads
    for (int t = 0; t < 32; ++t) {
        const int d = t & 1;
        if (t < 31) STAGE(d ^ 1, t + 1);          // issue next tile's 8 loads
        COMPUTE(d);                               // 128 MFMA + 48 ds_read_b128
        __syncthreads();                          // drains next-tile vmcnt + cur ds reads
    }
#undef STAGE
#undef COMPUTE

    // ---- acc -> Cs [256][256] f16, granule-swizzled G = (col>>3)^(R&31) ----
    f16* Cs = (f16*)smem;
#pragma unroll
    for (int mf = 0; mf < 8; ++mf)
#pragma unroll
        for (int nf = 0; nf < 4; ++nf)
#pragma unroll
            for (int r = 0; r < 4; ++r) {
                const int R   = wrow + mf*16 + l4*4 + r;
                const int col = wcol + nf*16 + l15;
                const int G   = (col >> 3) ^ (R & 31);
                Cs[R*256 + G*8 + (col & 7)] = (f16)acc[mf][nf][r];
            }
    __syncthreads();

    // ---- fused epilogue: 8 (token,head) pairs per thread ----
#pragma unroll
    for (int p = 0; p < 8; ++p) {
        const int linear = p * 512 + tid;         // 0..4095
        const int t  = linear >> 4;               // token-in-tile 0..255
        const int hh = linear & 15;               // head-in-tile 0..15
        const int H  = bn * 16 + hh;              // global head 0..63
        const int g0 = (2*hh)     ^ (t & 31);
        const int g1 = (2*hh + 1) ^ (t & 31);
        f16x8 y0 = *(const f16x8*)(Cs + t*256 + g0*8);
        f16x8 y1 = *(const f16x8*)(Cs + t*256 + g1*8);
        const float* bb = bh + H * 16;

        float Bv[16];
#pragma unroll
        for (int j = 0; j < 8; ++j) {
            Bv[j]     = fast_tanh((float)y0[j] + bb[j])     * PI_F;
            Bv[j + 8] = fast_tanh((float)y1[j] + bb[j + 8]) * PI_F;
        }
        float s2 = 0.f;
#pragma unroll
        for (int j = 0; j < 16; ++j) s2 += Bv[j] * Bv[j];
        const float theta = 0.5f * sqrtf(s2);
        const float sinc  = (theta > 1e-8f) ? (__sinf(theta) / theta) : 1.0f;
        const float cs    = __cosf(theta);
        const float scale = -0.5f * sinc;
        float C[16];
#pragma unroll
        for (int j = 0; j < 16; ++j) C[j] = Bv[j] * scale;

        float4 v0 = {0,0,0,0}, v1 = {0,0,0,0}, v2 = {0,0,0,0}, v3 = {0,0,0,0};
        float4 v4 = {0,0,0,0}, v5 = {0,0,0,0}, v6 = {0,0,0,0}, v7 = {0,0,0,0};
        v0.x = cs;
        if (H < 10) {                              // syn: biv 6..15
            v1.z=C[0]; v1.w=C[1];
            v2.x=C[2]; v2.y=C[3]; v2.z=C[4]; v2.w=C[5];
            v3.x=C[6]; v3.y=C[7]; v3.z=C[8]; v3.w=C[9];
        } else if (H < 40) {                       // sem: vec 1..5 + biv 6..15
            v0.y=C[0]; v0.z=C[1]; v0.w=C[2];
            v1.x=C[3]; v1.y=C[4]; v1.z=C[5]; v1.w=C[6];
            v2.x=C[7]; v2.y=C[8]; v2.z=C[9]; v2.w=C[10];
            v3.x=C[11]; v3.y=C[12]; v3.z=C[13]; v3.w=C[14];
        } else {                                   // nar: biv 6..15 + quad 26..30
            v1.z=C[0]; v1.w=C[1];
            v2.x=C[2]; v2.y=C[3]; v2.z=C[4]; v2.w=C[5];
            v3.x=C[6]; v3.y=C[7]; v3.z=C[8]; v3.w=C[9];
            v6.z=C[10]; v6.w=C[11];
            v7.x=C[12]; v7.y=C[13]; v7.z=C[14];
        }
        float4* dst = (float4*)(Out + ((size_t)(m0 + t) * 64 + H) * 32);
        dst[0]=v0; dst[1]=v1; dst[2]=v2; dst[3]=v3;
        dst[4]=v4; dst[5]=v5; dst[6]=v6; dst[7]=v7;
    }
}

// ---------------------------------------------------------------------------
// FALLBACK gemm (R5 structure): fp32 A via global_load_lds, cvt at read.
// ---------------------------------------------------------------------------
__global__ __launch_bounds__(256)
void gemm_f32a_kernel(const float* __restrict__ X, const f16* __restrict__ Wt,
                      const float* __restrict__ bh, float* __restrict__ Out)
{
    __shared__ __align__(16) char smem[49152];
    float* Asf = (float*)smem;
    f16*   Bsh = (f16*)(smem + 32768);

    const int tid  = threadIdx.x;
    const int sw   = (blockIdx.x & 7) * 128 + (blockIdx.x >> 3);
    const int bm   = sw >> 3, bn = sw & 7;
    const int m0   = bm * 128, n0 = bn * 128;
    const int wave = tid >> 6, lane = tid & 63;
    const int wr   = (wave >> 1) * 64, wc = (wave & 1) * 64;
    const int l15  = lane & 15, l4 = lane >> 4;

    f32x4 acc[4][4] = {};

    for (int kt = 0; kt < 32; ++kt) {
        const int kof = kt * 64;
#pragma unroll
        for (int i = 0; i < 8; ++i) {
            const int ac = (wave*8 + i)*64 + lane;
            const int ar = ac >> 4;
            const int agc = (ac & 15) ^ (ar & 15);
            const float* src = X + (size_t)(m0 + ar) * 2048 + kof + agc * 4;
            __builtin_amdgcn_global_load_lds((const AS1 void*)src,
                (AS3 void*)(smem + (wave*8 + i) * 1024), 16, 0, 0);
        }
#pragma unroll
        for (int i = 0; i < 4; ++i) {
            const int bc = (wave*4 + i)*64 + lane;
            const int br = bc >> 3;
            const int bgc = (bc & 7) ^ (br & 7);
            const f16* src = Wt + (size_t)(n0 + br) * 2048 + kof + bgc * 8;
            __builtin_amdgcn_global_load_lds((const AS1 void*)src,
                (AS3 void*)(smem + 32768 + (wave*4 + i) * 1024), 16, 0, 0);
        }
        __syncthreads();
#pragma unroll
        for (int ks = 0; ks < 2; ++ks) {
            f16x8 af[4], bf[4];
#pragma unroll
            for (int mf = 0; mf < 4; ++mf) {
                const int r  = wr + mf*16 + l15;
                const int s  = r & 15;
                const float4 lo = *(const float4*)(Asf + ((size_t)r*16 + ((ks*8 + l4*2)     ^ s)) * 4);
                const float4 hi = *(const float4*)(Asf + ((size_t)r*16 + ((ks*8 + l4*2 + 1) ^ s)) * 4);
                f16x8 a;
                a[0]=(f16)lo.x; a[1]=(f16)lo.y; a[2]=(f16)lo.z; a[3]=(f16)lo.w;
                a[4]=(f16)hi.x; a[5]=(f16)hi.y; a[6]=(f16)hi.z; a[7]=(f16)hi.w;
                af[mf] = a;
            }
#pragma unroll
            for (int nf = 0; nf < 4; ++nf) {
                const int r = wc + nf*16 + l15;
                bf[nf] = *(const f16x8*)(Bsh + ((size_t)r*8 + ((ks*4 + l4) ^ (r & 7))) * 8);
            }
#pragma unroll
            for (int mf = 0; mf < 4; ++mf)
#pragma unroll
                for (int nf = 0; nf < 4; ++nf)
                    acc[mf][nf] = __builtin_amdgcn_mfma_f32_16x16x32_f16(af[mf], bf[nf], acc[mf][nf], 0, 0, 0);
        }
        __syncthreads();
    }

    f16* Cs = (f16*)smem;
#pragma unroll
    for (int mf = 0; mf < 4; ++mf)
#pragma unroll
        for (int nf = 0; nf < 4; ++nf)
#pragma unroll
            for (int r = 0; r < 4; ++r) {
                const int R = wr + mf*16 + l4*4 + r;
                const int col = wc + nf*16 + l15;
                const int G = (col >> 3) ^ (R & 15);
                Cs[R*128 + G*8 + (col & 7)] = (f16)acc[mf][nf][r];
            }
    __syncthreads();
#pragma unroll
    for (int p = 0; p < 4; ++p) {
        const int linear = p * 256 + tid;
        const int t  = linear >> 3;
        const int hh = linear & 7;
        const int H  = bn * 8 + hh;
        const int g0 = (2*hh)     ^ (t & 15);
        const int g1 = (2*hh + 1) ^ (t & 15);
        f16x8 y0 = *(const f16x8*)(Cs + t*128 + g0*8);
        f16x8 y1 = *(const f16x8*)(Cs + t*128 + g1*8);
        const float* bb = bh + H * 16;
        float Bv[16];
#pragma unroll
        for (int j = 0; j < 8; ++j) {
            Bv[j]     = fast_tanh((float)y0[j] + bb[j])     * PI_F;
            Bv[j + 8] = fast_tanh((float)y1[j] + bb[j + 8]) * PI_F;
        }
        float s2 = 0.f;
#pragma unroll
        for (int j = 0; j < 16; ++j) s2 += Bv[j] * Bv[j];
        const float theta = 0.5f * sqrtf(s2);
        const float sinc  = (theta > 1e-8f) ? (__sinf(theta) / theta) : 1.0f;
        const float cs    = __cosf(theta);
        const float scale = -0.5f * sinc;
        float C[16];
#pragma unroll
        for (int j = 0; j < 16; ++j) C[j] = Bv[j] * scale;
        float4 v0 = {0,0,0,0}, v1 = {0,0,0,0}, v2 = {0,0,0,0}, v3 = {0,0,0,0};
        float4 v4 = {0,0,0,0}, v5 = {0,0,0,0}, v6 = {0,0,0,0}, v7 = {0,0,0,0};
        v0.x = cs;
        if (H < 10) {
            v1.z=C[0]; v1.w=C[1];
            v2.x=C[2]; v2.y=C[3]; v2.z=C[4]; v2.w=C[5];
            v3.x=C[6]; v3.y=C[7]; v3.z=C[8]; v3.w=C[9];
        } else if (H < 40) {
            v0.y=C[0]; v0.z=C[1]; v0.w=C[2];
            v1.x=C[3]; v1.y=C[4]; v1.z=C[5]; v1.w=C[6];
            v2.x=C[7]; v2.y=C[8]; v2.z=C[9]; v2.w=C[10];
            v3.x=C[11]; v3.y=C[12]; v3.z=C[13]; v3.w=C[14];
        } else {
            v1.z=C[0]; v1.w=C[1];
            v2.x=C[2]; v2.y=C[3]; v2.z=C[4]; v2.w=C[5];
            v3.x=C[6]; v3.y=C[7]; v3.z=C[8]; v3.w=C[9];
            v6.z=C[10]; v6.w=C[11];
            v7.x=C[12]; v7.y=C[13]; v7.z=C[14];
        }
        float4* dst = (float4*)(Out + ((size_t)(m0 + t) * 64 + H) * 32);
        dst[0]=v0; dst[1]=v1; dst[2]=v2; dst[3]=v3;
        dst[4]=v4; dst[5]=v5; dst[6]=v6; dst[7]=v7;
    }
}

// ---------------------------------------------------------------------------
extern "C" void kernel_launch(void* const* d_in, const int* in_sizes, int n_in,
                              void* d_out, int out_size, void* d_ws, size_t ws_size,
                              hipStream_t stream)
{
    const float* x     = (const float*)d_in[0];
    const float* W_syn = (const float*)d_in[1];
    const float* b_syn = (const float*)d_in[2];
    const float* W_sem = (const float*)d_in[3];
    const float* b_sem = (const float*)d_in[4];
    const float* W_nar = (const float*)d_in[5];
    const float* b_nar = (const float*)d_in[6];

    // ws layout: Wt fp16 4MB | bh f32 (64KB slot) | Xh fp16 64MB
    const size_t WT_B = (size_t)4*1024*1024, BH_B = 65536;
    const size_t XH_B = (size_t)33554432 * 2;
    f16*   Wt = (f16*)d_ws;
    float* bh = (float*)((char*)d_ws + WT_B);
    f16*   Xh = (f16*)((char*)d_ws + WT_B + BH_B);
    float* Out = (float*)d_out;

    prep_kernel<<<2048, 256, 0, stream>>>(W_syn, b_syn, W_sem, b_sem, W_nar, b_nar, Wt, bh);
    if (ws_size >= WT_B + BH_B + XH_B) {
        convert_kernel<<<16384, 256, 0, stream>>>(x, Xh);
        gemm256_kernel<<<256, 512, 0, stream>>>(Xh, Wt, bh, Out);
    } else {
        gemm_f32a_kernel<<<1024, 256, 0, stream>>>(x, Wt, bh, Out);
    }
}